// Round 1
// baseline (260.523 us; speedup 1.0000x reference)
//
#include <hip/hip_runtime.h>

typedef _Float16 f16;
typedef __attribute__((ext_vector_type(8))) _Float16 half8;
typedef __attribute__((ext_vector_type(4))) _Float16 half4;
typedef __attribute__((ext_vector_type(4))) float f32x4;

#define DEVINL static __device__ __forceinline__

constexpr float NORMALIZER = 0.35355339059327373f;  // 64^-0.25
constexpr float RATIO      = 0.08838834764831845f;  // 1/sqrt(128)
constexpr float FEPS       = 1e-6f;

// ---------------- workspace layout (bytes) ----------------
constexpr size_t OFF_WQKVT = 0;                                   // [2304][768] f16
constexpr size_t OFF_WOT   = OFF_WQKVT + (size_t)2304*768*2;      // [768][768] f16
constexpr size_t OFF_PROJF = OFF_WOT   + (size_t)768*768*2;       // [128][64] f16 (pre-scaled)
constexpr size_t OFF_KS    = OFF_PROJF + (size_t)128*64*2;        // [48][128] f32
constexpr size_t OFF_KSP   = OFF_KS    + (size_t)48*128*4;        // [48*64][128] f32
constexpr size_t OFF_DEN   = OFF_KSP   + (size_t)48*64*128*4;     // [48][4096] f32
constexpr size_t OFF_KVST  = OFF_DEN   + (size_t)48*4096*4;       // [48][64][128] f16
constexpr size_t OFF_KVSP  = OFF_KVST  + (size_t)48*64*128*2;     // [8][48][128][64] f32
constexpr size_t OFF_X16   = OFF_KVSP  + (size_t)8*48*128*64*4;   // [16384][768] f16
constexpr size_t OFF_ATT   = OFF_X16;                              // alias (x16 dead after QKV GEMM)
constexpr size_t OFF_Q16   = OFF_X16 + (size_t)16384*768*2;
constexpr size_t OFF_K16   = OFF_Q16 + (size_t)16384*768*2;
constexpr size_t OFF_VT    = OFF_K16 + (size_t)16384*768*2;       // [48][64][4096] f16
constexpr size_t OFF_QP    = OFF_K16;                              // alias K16+VT (both dead by then)
constexpr size_t OFF_KPT   = OFF_VT  + (size_t)16384*768*2;       // [48][128][4096] f16

// ---------------- helpers ----------------
DEVINL void gload_lds16(const f16* g, f16* lds) {
  __builtin_amdgcn_global_load_lds(
      (const __attribute__((address_space(1))) void*)g,
      (__attribute__((address_space(3))) void*)lds, 16, 0, 0);
}

// Tile GEMM core: C[128 x BN] = A[128 x K] * Bt[BN x K]^T ; f16 in, f32 acc.
// 256 threads = 4 waves in 2x2; wave tile 64 x (BN/2).
template<int BN>
DEVINL void gemm_tile(const f16* A, int lda, const f16* Bt, int ldb, int K,
                      f16* As, f16* Bs, f32x4 (&acc)[4][BN/32])
{
  constexpr int NF = BN/32;
  const int t = threadIdx.x;
  const int w = t >> 6, lane = t & 63;
  const int g = lane >> 4, c = lane & 15;
  const int wr = w >> 1, wc = w & 1;
  const int srow = lane >> 2;
  const int sseg = (lane & 3) * 8;

#pragma unroll
  for (int i = 0; i < 4; ++i)
#pragma unroll
    for (int j = 0; j < NF; ++j)
      acc[i][j] = f32x4{0.f, 0.f, 0.f, 0.f};

  for (int k0 = 0; k0 < K; k0 += 32) {
#pragma unroll
    for (int r = 0; r < 2; ++r) {                 // A: 128 rows x 64B
      const int rowblk = (w + 4*r) * 16;
      gload_lds16(A + (size_t)(rowblk + srow) * lda + k0 + sseg, As + rowblk*32);
    }
#pragma unroll
    for (int r = 0; r < BN/64; ++r) {             // B: BN rows x 64B
      const int rowblk = (w + 4*r) * 16;
      gload_lds16(Bt + (size_t)(rowblk + srow) * ldb + k0 + sseg, Bs + rowblk*32);
    }
    __syncthreads();                               // drains vmcnt, data visible
    half8 av[4], bv[NF];
#pragma unroll
    for (int i = 0; i < 4; ++i)
      av[i] = *(const half8*)(As + (wr*64 + i*16 + c)*32 + g*8);
#pragma unroll
    for (int j = 0; j < NF; ++j)
      bv[j] = *(const half8*)(Bs + (wc*(BN/2) + j*16 + c)*32 + g*8);
#pragma unroll
    for (int i = 0; i < 4; ++i)
#pragma unroll
      for (int j = 0; j < NF; ++j)
        acc[i][j] = __builtin_amdgcn_mfma_f32_16x16x32_f16(av[i], bv[j], acc[i][j], 0, 0, 0);
    __syncthreads();                               // protect LDS for next stage
  }
}

// ---------------- cast / transpose kernels ----------------
__global__ __launch_bounds__(256) void k_cast_x(const float* __restrict__ X, f16* __restrict__ X16)
{
  const size_t i = ((size_t)blockIdx.x*256 + threadIdx.x) * 4;
  const float4 v = *(const float4*)(X + i);
  half4 h;
  h[0] = (f16)v.x; h[1] = (f16)v.y; h[2] = (f16)v.z; h[3] = (f16)v.w;
  *(half4*)(X16 + i) = h;
}

__global__ __launch_bounds__(256) void k_transpose_w(const float* __restrict__ W, f16* __restrict__ Wt)
{
  __shared__ float ls[64][65];
  const int t = threadIdx.x;
  const int k0 = blockIdx.x*64, n0 = blockIdx.y*64;
#pragma unroll
  for (int it = 0; it < 4; ++it) {
    const int r = it*16 + (t >> 4);
    const int cs = (t & 15) * 4;
    const float4 v = *(const float4*)(W + (size_t)(k0 + r)*768 + n0 + cs);
    ls[r][cs+0] = v.x; ls[r][cs+1] = v.y; ls[r][cs+2] = v.z; ls[r][cs+3] = v.w;
  }
  __syncthreads();
  const int n = t >> 2;
  const int seg = (t & 3) * 16;
  half8 ov[2];
#pragma unroll
  for (int i = 0; i < 16; ++i) ov[i>>3][i&7] = (f16)ls[seg + i][n];
  f16* dst = Wt + (size_t)(n0 + n)*768 + k0 + seg;
  *(half8*)dst = ov[0];
  *(half8*)(dst + 8) = ov[1];
}

__global__ __launch_bounds__(256) void k_cast_proj(const float* __restrict__ P, f16* __restrict__ PF)
{
  const int i = blockIdx.x*256 + threadIdx.x;   // 8192
  PF[i] = (f16)(NORMALIZER * P[i]);
}

// ---------------- QKV GEMM (writes Q,K normal; V transposed) ----------------
__global__ __launch_bounds__(256) void k_gemm_qkv(const f16* __restrict__ X16, const f16* __restrict__ WT,
    const float* __restrict__ bq, const float* __restrict__ bk, const float* __restrict__ bv,
    f16* __restrict__ Qo, f16* __restrict__ Ko, f16* __restrict__ VT)
{
  __shared__ f16 As[128*32], Bs[128*32];
  f32x4 acc[4][4];
  const int bx = blockIdx.x, by = blockIdx.y;    // (128, 18)
  gemm_tile<128>(X16 + (size_t)bx*128*768, 768, WT + (size_t)by*128*768, 768, 768, As, Bs, acc);
  const int t = threadIdx.x, w = t>>6, lane = t&63, g = lane>>4, c = lane&15;
  const int wr = w>>1, wc = w&1;
  const int nbase = by*128;
  const int which = nbase / 768;                 // 0:q 1:k 2:v (uniform per block)
  const int ncol0 = nbase % 768;
  const float* bias = which==0 ? bq : (which==1 ? bk : bv);
#pragma unroll
  for (int i = 0; i < 4; ++i) {
    const int row0 = bx*128 + wr*64 + i*16 + g*4;
#pragma unroll
    for (int j = 0; j < 4; ++j) {
      const int col = ncol0 + wc*64 + j*16 + c;
      const float bb = bias[col];
      if (which == 2) {
        const int b_ = row0 >> 12, l = row0 & 4095;
        const int hh = col >> 6, d = col & 63;
        half4 tmp;
#pragma unroll
        for (int r = 0; r < 4; ++r) tmp[r] = (f16)(acc[i][j][r] + bb);
        *(half4*)(VT + (((size_t)(b_*12 + hh)*64 + d)*4096 + l)) = tmp;
      } else {
        f16* dst = (which==0 ? Qo : Ko) + (size_t)row0*768 + col;
#pragma unroll
        for (int r = 0; r < 4; ++r) dst[(size_t)r*768] = (f16)(acc[i][j][r] + bb);
      }
    }
  }
}

// ---------------- feature kernels ----------------
// block: (lb in L/64, bh in 48). Computes dd[64l][128m] = q * (norm*proj)^T via MFMA,
// then exp(dd - diag - rowmax), q' to QP + den ; k-variant writes transposed KPT + ks partials.
DEVINL void feat_common(const f16* base, const f16* PROJF,
                        f16* qs, f16* ps, float* dd, float* diag_s)
{
  const int t = threadIdx.x, w = t >> 6, lane = t & 63;
#pragma unroll
  for (int it = 0; it < 2; ++it) {
    const int rowblk = it*32 + w*8;
    gload_lds16(base + (size_t)(rowblk + (lane>>3))*768 + (lane&7)*8, qs + rowblk*64);
  }
#pragma unroll
  for (int it = 0; it < 4; ++it) {
    const int rowblk = it*32 + w*8;
    gload_lds16(PROJF + (size_t)(rowblk + (lane>>3))*64 + (lane&7)*8, ps + rowblk*64);
  }
  __syncthreads();
  if (t < 64) {
    float s = 0.f;
    for (int d = 0; d < 64; ++d) { const float qv = (float)qs[t*64 + d]; s += qv*qv; }
    diag_s[t] = 0.0625f * s;   // 0.5 * (normalizer^2) * sum q^2
  }
  const int g = lane >> 4, c = lane & 15;
  const int wr = w >> 1, wc = w & 1;
  f32x4 facc[2][4];
#pragma unroll
  for (int i = 0; i < 2; ++i)
#pragma unroll
    for (int j = 0; j < 4; ++j) facc[i][j] = f32x4{0.f,0.f,0.f,0.f};
#pragma unroll
  for (int kk = 0; kk < 2; ++kk) {
    half8 av[2], bv[4];
#pragma unroll
    for (int i = 0; i < 2; ++i) av[i] = *(const half8*)(qs + (wr*32 + i*16 + c)*64 + kk*32 + g*8);
#pragma unroll
    for (int j = 0; j < 4; ++j) bv[j] = *(const half8*)(ps + (wc*64 + j*16 + c)*64 + kk*32 + g*8);
#pragma unroll
    for (int i = 0; i < 2; ++i)
#pragma unroll
      for (int j = 0; j < 4; ++j)
        facc[i][j] = __builtin_amdgcn_mfma_f32_16x16x32_f16(av[i], bv[j], facc[i][j], 0, 0, 0);
  }
#pragma unroll
  for (int i = 0; i < 2; ++i)
#pragma unroll
    for (int j = 0; j < 4; ++j)
#pragma unroll
      for (int r = 0; r < 4; ++r)
        dd[(wr*32 + i*16 + g*4 + r)*129 + wc*64 + j*16 + c] = facc[i][j][r];
  __syncthreads();
}

__global__ __launch_bounds__(256) void k_qfeat(const f16* __restrict__ Q, const f16* __restrict__ PROJF,
    const float* __restrict__ KS, f16* __restrict__ QP, float* __restrict__ DEN)
{
  __shared__ f16 qs[64*64];
  __shared__ f16 ps[128*64];
  __shared__ float dd[64*129];
  __shared__ float diag_s[64];
  __shared__ float ks_s[128];
  const int t = threadIdx.x;
  const int lb = blockIdx.x, bh = blockIdx.y;
  const int b = bh / 12, h = bh - b*12;
  if (t < 128) ks_s[t] = KS[bh*128 + t];
  feat_common(Q + ((size_t)(b*4096 + lb*64))*768 + h*64, PROJF, qs, ps, dd, diag_s);
  const int l = t >> 2, s = t & 3;
  float v[32];
#pragma unroll
  for (int j = 0; j < 32; ++j) v[j] = dd[l*129 + s*32 + j];
  float mx = v[0];
#pragma unroll
  for (int j = 1; j < 32; ++j) mx = fmaxf(mx, v[j]);
  mx = fmaxf(mx, __shfl_xor(mx, 1));
  mx = fmaxf(mx, __shfl_xor(mx, 2));
  const float off = diag_s[l] + mx;
  half8 ov[4];
  float dp = 0.f;
#pragma unroll
  for (int j = 0; j < 32; ++j) {
    const float e = RATIO * (__expf(v[j] - off) + FEPS);
    ov[j>>3][j&7] = (f16)e;
    dp += e * ks_s[s*32 + j];
  }
  dp += __shfl_xor(dp, 1);
  dp += __shfl_xor(dp, 2);
  const size_t lrow = (size_t)bh*4096 + lb*64 + l;
  if (s == 0) DEN[lrow] = dp;
  f16* dst = QP + lrow*128 + s*32;
#pragma unroll
  for (int q8 = 0; q8 < 4; ++q8) *(half8*)(dst + q8*8) = ov[q8];
}

__global__ __launch_bounds__(256) void k_kfeat(const f16* __restrict__ Kin, const f16* __restrict__ PROJF,
    f16* __restrict__ KPT, float* __restrict__ KSP)
{
  __shared__ f16 qs[64*64];
  __shared__ f16 ps[128*64];
  __shared__ float dd[64*129];
  __shared__ float diag_s[64];
  const int t = threadIdx.x;
  const int lb = blockIdx.x, bh = blockIdx.y;
  const int b = bh / 12, h = bh - b*12;
  feat_common(Kin + ((size_t)(b*4096 + lb*64))*768 + h*64, PROJF, qs, ps, dd, diag_s);
  const int l = t >> 2, s = t & 3;
  float v[32];
#pragma unroll
  for (int j = 0; j < 32; ++j) v[j] = dd[l*129 + s*32 + j];
  float mx = v[0];
#pragma unroll
  for (int j = 1; j < 32; ++j) mx = fmaxf(mx, v[j]);
  mx = fmaxf(mx, __shfl_xor(mx, 1));
  mx = fmaxf(mx, __shfl_xor(mx, 2));
  const float off = diag_s[l] + mx;
#pragma unroll
  for (int j = 0; j < 32; ++j) dd[l*129 + s*32 + j] = RATIO * (__expf(v[j] - off) + FEPS);
  __syncthreads();
  if (t < 128) {                   // ks partial over this l-block
    float sm = 0.f;
    for (int l2 = 0; l2 < 64; ++l2) sm += dd[l2*129 + t];
    KSP[((size_t)bh*64 + lb)*128 + t] = sm;
  }
  const int m = t >> 1, hf = t & 1; // transposed store k' -> [bh][m][L]
  half8 ov[4];
#pragma unroll
  for (int i2 = 0; i2 < 32; ++i2) ov[i2>>3][i2&7] = (f16)dd[(hf*32 + i2)*129 + m];
  f16* dst = KPT + ((size_t)bh*128 + m)*4096 + lb*64 + hf*32;
#pragma unroll
  for (int q8 = 0; q8 < 4; ++q8) *(half8*)(dst + q8*8) = ov[q8];
}

// ---------------- kvs: [48] (128m x 64d) = k'^T @ v, chunked over L ----------------
__global__ __launch_bounds__(256) void k_kvs(const f16* __restrict__ KPT, const f16* __restrict__ VT,
    float* __restrict__ KVSP)
{
  __shared__ f16 As[128*32], Bs[64*32];
  f32x4 acc[4][2];
  const int chunk = blockIdx.x, bh = blockIdx.y;   // (8, 48)
  gemm_tile<64>(KPT + (size_t)bh*128*4096 + chunk*512, 4096,
                VT  + (size_t)bh*64*4096  + chunk*512, 4096, 512, As, Bs, acc);
  const int t = threadIdx.x, w = t>>6, lane = t&63, g = lane>>4, c = lane&15;
  const int wr = w>>1, wc = w&1;
  float* dst = KVSP + (size_t)(chunk*48 + bh)*128*64;
#pragma unroll
  for (int i = 0; i < 4; ++i) {
    const int row0 = wr*64 + i*16 + g*4;
#pragma unroll
    for (int j = 0; j < 2; ++j) {
      const int col = wc*32 + j*16 + c;
#pragma unroll
      for (int r = 0; r < 4; ++r) dst[(size_t)(row0 + r)*64 + col] = acc[i][j][r];
    }
  }
}

__global__ __launch_bounds__(256) void k_reduce(const float* __restrict__ KVSP, const float* __restrict__ KSP,
    f16* __restrict__ KVST, float* __restrict__ KS)
{
  const int i = blockIdx.x*256 + threadIdx.x;
  if (i < 48*128*64) {                 // kvs reduce + transpose to [bh][d][m]
    const int bh = i >> 13, md = i & 8191, m = md >> 6, d = md & 63;
    float s = 0.f;
#pragma unroll
    for (int c = 0; c < 8; ++c) s += KVSP[((size_t)(c*48 + bh)*128 + m)*64 + d];
    KVST[((size_t)bh*64 + d)*128 + m] = (f16)s;
  }
  if (i < 48*128) {                    // ks reduce
    const int bh = i >> 7, m = i & 127;
    float s = 0.f;
#pragma unroll 8
    for (int lb = 0; lb < 64; ++lb) s += KSP[((size_t)bh*64 + lb)*128 + m];
    KS[i] = s;
  }
}

// ---------------- num GEMM + normalize -> ATT [bh][l][d] f16 ----------------
__global__ __launch_bounds__(256) void k_num(const f16* __restrict__ QP, const f16* __restrict__ KVST,
    const float* __restrict__ DEN, f16* __restrict__ ATT)
{
  __shared__ f16 As[128*32], Bs[64*32];
  f32x4 acc[4][2];
  const int bx = blockIdx.x, bh = blockIdx.y;      // (32, 48)
  gemm_tile<64>(QP + ((size_t)bh*4096 + bx*128)*128, 128,
                KVST + (size_t)bh*64*128, 128, 128, As, Bs, acc);
  const int t = threadIdx.x, w = t>>6, lane = t&63, g = lane>>4, c = lane&15;
  const int wr = w>>1, wc = w&1;
#pragma unroll
  for (int i = 0; i < 4; ++i) {
    const int l0 = bx*128 + wr*64 + i*16 + g*4;
#pragma unroll
    for (int j = 0; j < 2; ++j) {
      const int d = wc*32 + j*16 + c;
#pragma unroll
      for (int r = 0; r < 4; ++r) {
        const float den = DEN[(size_t)bh*4096 + l0 + r];
        ATT[((size_t)bh*4096 + l0 + r)*64 + d] = (f16)(acc[i][j][r] / den);
      }
    }
  }
}

// ---------------- final GEMM ----------------
__global__ __launch_bounds__(256) void k_gemm_out(const f16* __restrict__ ATT, const f16* __restrict__ WOT,
    const float* __restrict__ bo, float* __restrict__ out)
{
  __shared__ f16 As[128*32], Bs[128*32];
  f32x4 acc[4][4];
  const int bx = blockIdx.x, by = blockIdx.y;      // (128, 6)
  gemm_tile<128>(ATT + (size_t)bx*128*768, 768, WOT + (size_t)by*128*768, 768, 768, As, Bs, acc);
  const int t = threadIdx.x, w = t>>6, lane = t&63, g = lane>>4, c = lane&15;
  const int wr = w>>1, wc = w&1;
#pragma unroll
  for (int i = 0; i < 4; ++i) {
    const int row0 = bx*128 + wr*64 + i*16 + g*4;
#pragma unroll
    for (int j = 0; j < 4; ++j) {
      const int col = by*128 + wc*64 + j*16 + c;
      const float bb = bo[col];
#pragma unroll
      for (int r = 0; r < 4; ++r) out[(size_t)(row0 + r)*768 + col] = acc[i][j][r] + bb;
    }
  }
}

// ---------------- launcher ----------------
extern "C" void kernel_launch(void* const* d_in, const int* in_sizes, int n_in,
                              void* d_out, int out_size, void* d_ws, size_t ws_size,
                              hipStream_t stream)
{
  const float* x    = (const float*)d_in[0];
  const float* Wq   = (const float*)d_in[1];
  const float* bq   = (const float*)d_in[2];
  const float* Wk   = (const float*)d_in[3];
  const float* bk   = (const float*)d_in[4];
  const float* Wv   = (const float*)d_in[5];
  const float* bv   = (const float*)d_in[6];
  const float* Wo   = (const float*)d_in[7];
  const float* bo   = (const float*)d_in[8];
  const float* proj = (const float*)d_in[9];
  float* out = (float*)d_out;
  char* ws = (char*)d_ws;

  f16*   WQKVT = (f16*)(ws + OFF_WQKVT);
  f16*   WOT   = (f16*)(ws + OFF_WOT);
  f16*   PROJF = (f16*)(ws + OFF_PROJF);
  float* KS    = (float*)(ws + OFF_KS);
  float* KSP   = (float*)(ws + OFF_KSP);
  float* DEN   = (float*)(ws + OFF_DEN);
  f16*   KVST  = (f16*)(ws + OFF_KVST);
  float* KVSP  = (float*)(ws + OFF_KVSP);
  f16*   X16   = (f16*)(ws + OFF_X16);
  f16*   ATT   = (f16*)(ws + OFF_ATT);
  f16*   Q16   = (f16*)(ws + OFF_Q16);
  f16*   K16   = (f16*)(ws + OFF_K16);
  f16*   VT    = (f16*)(ws + OFF_VT);
  f16*   QP    = (f16*)(ws + OFF_QP);
  f16*   KPT   = (f16*)(ws + OFF_KPT);

  k_cast_x<<<12288, 256, 0, stream>>>(x, X16);
  k_transpose_w<<<dim3(12,12), 256, 0, stream>>>(Wq, WQKVT);
  k_transpose_w<<<dim3(12,12), 256, 0, stream>>>(Wk, WQKVT + (size_t)768*768);
  k_transpose_w<<<dim3(12,12), 256, 0, stream>>>(Wv, WQKVT + (size_t)2*768*768);
  k_transpose_w<<<dim3(12,12), 256, 0, stream>>>(Wo, WOT);
  k_cast_proj<<<32, 256, 0, stream>>>(proj, PROJF);

  k_gemm_qkv<<<dim3(128,18), 256, 0, stream>>>(X16, WQKVT, bq, bk, bv, Q16, K16, VT);
  k_kfeat<<<dim3(64,48), 256, 0, stream>>>(K16, PROJF, KPT, KSP);
  k_kvs<<<dim3(8,48), 256, 0, stream>>>(KPT, VT, KVSP);
  k_reduce<<<1536, 256, 0, stream>>>(KVSP, KSP, KVST, KS);
  k_qfeat<<<dim3(64,48), 256, 0, stream>>>(Q16, PROJF, KS, QP, DEN);
  k_num<<<dim3(32,48), 256, 0, stream>>>(QP, KVST, DEN, ATT);
  k_gemm_out<<<dim3(128,6), 256, 0, stream>>>(ATT, WOT, bo, out);
}